// Round 6
// baseline (46.141 us; speedup 1.0000x reference)
//
#include <hip/hip_runtime.h>
#include <math.h>

namespace {

constexpr int D   = 32;
constexpr int H   = 128;
constexpr int WS  = 36;    // padded row stride: lane-groups start at bank 4*kq -> <=2-way aliasing (free)
constexpr int L   = 16;    // lanes per batch element (R5: 8). 2x waves -> 4/SIMD, VGPR ~invariant
constexpr int THREADS = 256;      // 4 waves
constexpr int EPB = THREADS / L;  // 16 elements per block
constexpr int KPL = H / L;        // 8 hidden units per lane

__device__ __forceinline__ float fast_tanh(float z) {
  float e = __expf(2.0f * z);
  return 1.0f - 2.0f * __builtin_amdgcn_rcpf(e + 1.0f);
}

// launch_bounds(256,1): R3's (256,2) capped VGPRs -> scratch spills (WRITE 64KB->366MB).
// #pragma unroll 2 (NOT full): full unroll hoists ~1100 floats of LDS loads -> spills
// even at 256 VGPRs (R4: 134us). unroll 2 -> VGPR=112, no spill (R5: 30us).
__global__ __launch_bounds__(THREADS, 1) void fpe_kernel(
    const float* __restrict__ xg, const float* __restrict__ tg,
    const float* __restrict__ betag, const float* __restrict__ W1g,
    const float* __restrict__ b1g, const float* __restrict__ W2g,
    const float* __restrict__ b2g, float* __restrict__ out, int Btot)
{
  __shared__ float W1T[H * WS];  // W1T[k][i], i<33; [33]=b1_k, [34]=c_k
  __shared__ float W2r[H * WS];  // W2r[k][j], j<32
  __shared__ float b2s[D];

  const int tid = threadIdx.x;
  const int e   = tid >> 4;      // element within block
  const int kq  = tid & (L - 1); // k-sixteenth
  const int b   = blockIdx.x * EPB + e;
  const bool valid = (b < Btot);
  const int bc = valid ? b : 0;

  // ---- per-element global loads issued first (latency hides under staging)
  float4 xr[8];
  const float4* xv = reinterpret_cast<const float4*>(xg + (size_t)bc * D);
  #pragma unroll
  for (int q = 0; q < 8; ++q) xr[q] = xv[q];
  const float tval = tg[bc];
  const float hb   = 0.5f * betag[bc];

  // ---- stage weights (W1 transposed), biases
  for (int n = tid; n < 33 * H; n += THREADS) {
    int i = n >> 7, k = n & (H - 1);
    W1T[k * WS + i] = W1g[n];
  }
  for (int n = tid; n < H * D; n += THREADS) {
    int k = n >> 5, j = n & (D - 1);
    W2r[k * WS + j] = W2g[n];
  }
  if (tid < H) W1T[tid * WS + 33] = b1g[tid];
  if (tid < D) b2s[tid] = b2g[tid];
  __syncthreads();

  // c_k = sum_j W1[j,k]*W2[k,j] (batch-independent)
  if (tid < H) {
    const float* wa = W1T + tid * WS;
    const float* wb = W2r + tid * WS;
    float c0 = 0, c1 = 0, c2 = 0, c3 = 0;
    #pragma unroll
    for (int j = 0; j < D; j += 4) {
      c0 = fmaf(wa[j + 0], wb[j + 0], c0);
      c1 = fmaf(wa[j + 1], wb[j + 1], c1);
      c2 = fmaf(wa[j + 2], wb[j + 2], c2);
      c3 = fmaf(wa[j + 3], wb[j + 3], c3);
    }
    W1T[tid * WS + 34] = (c0 + c1) + (c2 + c3);
  }
  __syncthreads();

  // ---- unpack x
  float x[D];
  #pragma unroll
  for (int q = 0; q < 8; ++q) {
    x[4*q+0] = xr[q].x; x[4*q+1] = xr[q].y; x[4*q+2] = xr[q].z; x[4*q+3] = xr[q].w;
  }

  float ps[D], pd[D], hreg[KPL];
  #pragma unroll
  for (int j = 0; j < D; ++j) { ps[j] = 0.0f; pd[j] = 0.0f; }

  // ================= Pass A: z, h (regs), partial s & ds/dt over this lane's k's
  #pragma unroll 2
  for (int n = 0; n < KPL; ++n) {
    const int k = L * n + kq;
    const float4* wa = reinterpret_cast<const float4*>(W1T + k * WS);
    const float4* wb = reinterpret_cast<const float4*>(W2r + k * WS);
    const float4 a8 = wa[8];                 // {W1[32,k], b1_k, c_k, pad}
    float z0 = a8.y, z1 = 0.0f, z2 = 0.0f, z3 = 0.0f;
    #pragma unroll
    for (int q = 0; q < 8; ++q) {
      float4 a = wa[q];
      z0 = fmaf(a.x, x[4*q+0], z0);
      z1 = fmaf(a.y, x[4*q+1], z1);
      z2 = fmaf(a.z, x[4*q+2], z2);
      z3 = fmaf(a.w, x[4*q+3], z3);
    }
    float z  = ((z0 + z1) + (z2 + z3)) + a8.x * tval;
    float hh = fast_tanh(z);
    hreg[n] = hh;
    float g = 1.0f - hh * hh;
    float r = g * a8.x;
    #pragma unroll
    for (int q = 0; q < 8; ++q) {
      float4 w2 = wb[q];
      ps[4*q+0] = fmaf(w2.x, hh, ps[4*q+0]);
      ps[4*q+1] = fmaf(w2.y, hh, ps[4*q+1]);
      ps[4*q+2] = fmaf(w2.z, hh, ps[4*q+2]);
      ps[4*q+3] = fmaf(w2.w, hh, ps[4*q+3]);
      pd[4*q+0] = fmaf(w2.x, r,  pd[4*q+0]);
      pd[4*q+1] = fmaf(w2.y, r,  pd[4*q+1]);
      pd[4*q+2] = fmaf(w2.z, r,  pd[4*q+2]);
      pd[4*q+3] = fmaf(w2.w, r,  pd[4*q+3]);
    }
  }

  // ---- allreduce s, dsdt across the 16 lanes of this element
  #pragma unroll
  for (int j = 0; j < D; ++j) {
    ps[j] += __shfl_xor(ps[j], 1);
    ps[j] += __shfl_xor(ps[j], 2);
    ps[j] += __shfl_xor(ps[j], 4);
    ps[j] += __shfl_xor(ps[j], 8);
    pd[j] += __shfl_xor(pd[j], 1);
    pd[j] += __shfl_xor(pd[j], 2);
    pd[j] += __shfl_xor(pd[j], 4);
    pd[j] += __shfl_xor(pd[j], 8);
  }

  // x <- v = 2s + x ; pd <- A = dsdt - hb*s   (ps dies here; shrinks live set)
  #pragma unroll
  for (int q = 0; q < 8; ++q) {
    float4 bq = reinterpret_cast<const float4*>(b2s)[q];
    float s0 = ps[4*q+0] + bq.x, s1 = ps[4*q+1] + bq.y;
    float s2 = ps[4*q+2] + bq.z, s3 = ps[4*q+3] + bq.w;
    x[4*q+0] = fmaf(2.0f, s0, x[4*q+0]);
    x[4*q+1] = fmaf(2.0f, s1, x[4*q+1]);
    x[4*q+2] = fmaf(2.0f, s2, x[4*q+2]);
    x[4*q+3] = fmaf(2.0f, s3, x[4*q+3]);
    pd[4*q+0] = fmaf(-hb, s0, pd[4*q+0]);
    pd[4*q+1] = fmaf(-hb, s1, pd[4*q+1]);
    pd[4*q+2] = fmaf(-hb, s2, pd[4*q+2]);
    pd[4*q+3] = fmaf(-hb, s3, pd[4*q+3]);
  }

  // ================= Pass B: q_k and partial grad
  float pg[D];
  #pragma unroll
  for (int j = 0; j < D; ++j) pg[j] = 0.0f;

  #pragma unroll 2
  for (int n = 0; n < KPL; ++n) {
    const int k = L * n + kq;
    const float4* wa = reinterpret_cast<const float4*>(W1T + k * WS);
    const float4* wb = reinterpret_cast<const float4*>(W2r + k * WS);

    float m0 = 0, m1 = 0, m2 = 0, m3 = 0;
    #pragma unroll
    for (int q = 0; q < 8; ++q) {
      float4 w2 = wb[q];
      m0 = fmaf(w2.x, x[4*q+0], m0);
      m1 = fmaf(w2.y, x[4*q+1], m1);
      m2 = fmaf(w2.z, x[4*q+2], m2);
      m3 = fmaf(w2.w, x[4*q+3], m3);
    }
    float m  = (m0 + m1) + (m2 + m3);
    float hh = hreg[n];
    float g  = 1.0f - hh * hh;
    float c  = wa[8].z;
    float qk = g * fmaf(-2.0f * c, hh, m);

    #pragma unroll
    for (int q = 0; q < 8; ++q) {
      float4 a = wa[q];
      pg[4*q+0] = fmaf(a.x, qk, pg[4*q+0]);
      pg[4*q+1] = fmaf(a.y, qk, pg[4*q+1]);
      pg[4*q+2] = fmaf(a.z, qk, pg[4*q+2]);
      pg[4*q+3] = fmaf(a.w, qk, pg[4*q+3]);
    }
  }

  // ---- allreduce grad partials
  #pragma unroll
  for (int j = 0; j < D; ++j) {
    pg[j] += __shfl_xor(pg[j], 1);
    pg[j] += __shfl_xor(pg[j], 2);
    pg[j] += __shfl_xor(pg[j], 4);
    pg[j] += __shfl_xor(pg[j], 8);
  }

  // ---- distributed L1: lane kq handles j = 2*kq, 2*kq+1   (pd holds A)
  const int j0 = 2 * kq;
  float acc = fabsf(fmaf(-hb, pg[j0+0], pd[j0+0]))
            + fabsf(fmaf(-hb, pg[j0+1], pd[j0+1]));
  acc += __shfl_xor(acc, 1);
  acc += __shfl_xor(acc, 2);
  acc += __shfl_xor(acc, 4);
  acc += __shfl_xor(acc, 8);

  if (valid && kq == 0) out[b] = acc * (1.0f / 32.0f);
}

} // namespace

extern "C" void kernel_launch(void* const* d_in, const int* in_sizes, int n_in,
                              void* d_out, int out_size, void* d_ws, size_t ws_size,
                              hipStream_t stream) {
  const float* x    = (const float*)d_in[0];
  const float* t    = (const float*)d_in[1];
  const float* beta = (const float*)d_in[2];
  const float* W1   = (const float*)d_in[3];
  const float* b1   = (const float*)d_in[4];
  const float* W2   = (const float*)d_in[5];
  const float* b2   = (const float*)d_in[6];
  float* out = (float*)d_out;

  const int Btot = in_sizes[1];  // t is [B,1]
  const int grid = (Btot + EPB - 1) / EPB;
  hipLaunchKernelGGL(fpe_kernel, dim3(grid), dim3(THREADS), 0, stream,
                     x, t, beta, W1, b1, W2, b2, out, Btot);
}

// Round 7
// 10.409 us; speedup vs baseline: 4.4329x; 4.4329x over previous
//
#include <hip/hip_runtime.h>
#include <math.h>

namespace {

typedef _Float16 f16;
typedef _Float16 f16x8 __attribute__((ext_vector_type(8)));
typedef _Float16 f16x4 __attribute__((ext_vector_type(4)));
typedef float    f32x4 __attribute__((ext_vector_type(4)));

constexpr int D  = 32;
constexpr int H  = 128;
constexpr int S1 = 40;    // f16 row stride for K=32 operands  (80 B, mult of 16)
constexpr int S2 = 136;   // f16 row stride for K=128 operands (272 B, mult of 16)
constexpr int THREADS = 256;   // 4 waves
constexpr int BPW = 16;        // batch rows per wave (= MFMA N)
constexpr int BPB = 64;        // batch rows per block

__device__ __forceinline__ float fast_tanh(float z) {
  float e = __expf(2.0f * z);
  return 1.0f - 2.0f * __builtin_amdgcn_rcpf(e + 1.0f);
}

__device__ __forceinline__ f32x4 mfma16(f16x8 a, f16x8 b, f32x4 c) {
  return __builtin_amdgcn_mfma_f32_16x16x32_f16(a, b, c, 0, 0, 0);
}

// Transposed formulation: batch = N/col dim (lane&15) of every MFMA, so each
// stage's C-frag (col=lane&15, row=(lane>>4)*4+r — m89-verified) matches the
// next stage's B-operand (col=lane&15, k=(lane>>4)*8+r) after a same-wave LDS
// round-trip (in-order per wave -> no barriers in the compute phase).
__global__ __launch_bounds__(THREADS, 1) void fpe_mfma(
    const float* __restrict__ xg, const float* __restrict__ tg,
    const float* __restrict__ betag, const float* __restrict__ W1g,
    const float* __restrict__ b1g, const float* __restrict__ W2g,
    const float* __restrict__ b2g, float* __restrict__ out, int Btot)
{
  __shared__ alignas(16) f16 W1T[H * S1];       // [h][i]: W1^T x-part, A of Z
  __shared__ alignas(16) f16 W1X[D * S2];       // [j][k]: W1 x-part,   A of G
  __shared__ alignas(16) f16 W2R[H * S1];       // [k][j]: W2,          A of M
  __shared__ alignas(16) f16 W2T[D * S2];       // [j][k]: W2^T,        A of S/dsdt
  __shared__ alignas(16) float b1s[H];
  __shared__ alignas(16) float cks[H];          // c_k = sum_j W1[j,k] W2[k,j]
  __shared__ alignas(16) float b2s[D];
  __shared__ alignas(16) f16  w132h[H];         // W1[32,k] (t-row)
  __shared__ alignas(16) f16 pbuf[4][BPW * S2]; // per wave: h, then q
  __shared__ alignas(16) f16 vbuf[4][BPW * S1]; // per wave: v

  const int tid = threadIdx.x;

  // ---- stage weights once per block (f16, both orientations)
  for (int n = tid; n < D * H; n += THREADS) {
    int i = n >> 7, k = n & (H - 1);            // W1[i][k], i<32
    f16 w = (f16)W1g[n];
    W1T[k * S1 + i] = w;
    W1X[i * S2 + k] = w;
  }
  for (int n = tid; n < H * D; n += THREADS) {
    int k = n >> 5, j = n & (D - 1);            // W2[k][j]
    f16 w = (f16)W2g[n];
    W2R[k * S1 + j] = w;
    W2T[j * S2 + k] = w;
  }
  if (tid < H) { w132h[tid] = (f16)W1g[D * H + tid]; b1s[tid] = b1g[tid]; }
  if (tid < D) b2s[tid] = b2g[tid];
  __syncthreads();
  if (tid < H) {
    float c = 0.f;
    #pragma unroll
    for (int j = 0; j < D; ++j)
      c += (float)W1T[tid * S1 + j] * (float)W2R[tid * S1 + j];
    cks[tid] = c;
  }
  __syncthreads();

  const int wv  = tid >> 6;
  const int ln  = tid & 63;
  const int col = ln & 15;                      // batch column
  const int g4  = ln >> 4;                      // 16-lane group
  const int b0  = blockIdx.x * BPB + wv * BPW;
  if (b0 >= Btot) return;
  const int batch = min(b0 + col, Btot - 1);

  f16* pb = pbuf[wv];
  f16* vb = vbuf[wv];

  // ---- per-element global loads (issue all up front)
  const float* xrow = xg + (size_t)batch * D;
  const float4 xk0 = *(const float4*)(xrow + 8 * g4);       // B-frag of X^T
  const float4 xk1 = *(const float4*)(xrow + 8 * g4 + 4);
  const float4 xc0 = *(const float4*)(xrow + 4 * g4);       // C-layout x, om=0
  const float4 xc1 = *(const float4*)(xrow + 16 + 4 * g4);  // om=1
  const float tval = tg[batch];
  const float hb   = 0.5f * betag[batch];

  f16x8 bx;
  bx[0] = (f16)xk0.x; bx[1] = (f16)xk0.y; bx[2] = (f16)xk0.z; bx[3] = (f16)xk0.w;
  bx[4] = (f16)xk1.x; bx[5] = (f16)xk1.y; bx[6] = (f16)xk1.z; bx[7] = (f16)xk1.w;

  // ===== Z = W1^T X^T (K=32) + rank-1 t + b1 -> h (kept in C-frags + LDS f16)
  float hC[8][4];
  #pragma unroll
  for (int hm = 0; hm < 8; ++hm) {
    f16x8 a = *(const f16x8*)&W1T[(16 * hm + col) * S1 + 8 * g4];
    f32x4 zero = {0.f, 0.f, 0.f, 0.f};
    f32x4 z = mfma16(a, bx, zero);
    float4 b1v = *(const float4*)&b1s[16 * hm + 4 * g4];
    f16x4 wtv  = *(const f16x4*)&w132h[16 * hm + 4 * g4];
    f16x4 hv;
    #pragma unroll
    for (int r = 0; r < 4; ++r) {
      float zz = z[r] + ((const float*)&b1v)[r] + (float)wtv[r] * tval;
      float hh = fast_tanh(zz);
      hC[hm][r] = hh;
      hv[r] = (f16)hh;
    }
    *(f16x4*)&pb[col * S2 + 16 * hm + 4 * g4] = hv;
  }

  // ===== S^T = W2^T H^T + b2 ; dsdt^T = W2^T R^T, R = g .* W1[32,:] (K=128)
  f32x4 sT[2], dT[2];
  sT[0] = {0.f,0.f,0.f,0.f}; sT[1] = {0.f,0.f,0.f,0.f};
  dT[0] = {0.f,0.f,0.f,0.f}; dT[1] = {0.f,0.f,0.f,0.f};
  #pragma unroll
  for (int ks = 0; ks < 4; ++ks) {
    f16x8 hvf = *(const f16x8*)&pb[col * S2 + 32 * ks + 8 * g4];
    f16x8 wv8 = *(const f16x8*)&w132h[32 * ks + 8 * g4];
    f16x8 rv;
    #pragma unroll
    for (int r = 0; r < 8; ++r) {
      float hf = (float)hvf[r];
      float gg = fmaf(-hf, hf, 1.0f);
      rv[r] = (f16)(gg * (float)wv8[r]);
    }
    #pragma unroll
    for (int om = 0; om < 2; ++om) {
      f16x8 a = *(const f16x8*)&W2T[(16 * om + col) * S2 + 32 * ks + 8 * g4];
      sT[om] = mfma16(a, hvf, sT[om]);
      dT[om] = mfma16(a, rv,  dT[om]);
    }
  }
  // s += b2 ; v = 2s + x -> vbuf (f16)
  #pragma unroll
  for (int om = 0; om < 2; ++om) {
    float4 b2v = *(const float4*)&b2s[16 * om + 4 * g4];
    float4 xcv = om ? xc1 : xc0;
    f16x4 vv;
    #pragma unroll
    for (int r = 0; r < 4; ++r) {
      sT[om][r] += ((const float*)&b2v)[r];
      vv[r] = (f16)fmaf(2.0f, sT[om][r], ((const float*)&xcv)[r]);
    }
    *(f16x4*)&vb[col * S1 + 16 * om + 4 * g4] = vv;
  }

  // ===== M^T = W2 V^T (K=32) ; Q = g .* (M - 2 c .* H) -> pbuf (overwrite h)
  {
    f16x8 bv = *(const f16x8*)&vb[col * S1 + 8 * g4];
    #pragma unroll
    for (int hm = 0; hm < 8; ++hm) {
      f16x8 a = *(const f16x8*)&W2R[(16 * hm + col) * S1 + 8 * g4];
      f32x4 zero = {0.f, 0.f, 0.f, 0.f};
      f32x4 m = mfma16(a, bv, zero);
      float4 cv = *(const float4*)&cks[16 * hm + 4 * g4];
      f16x4 qv;
      #pragma unroll
      for (int r = 0; r < 4; ++r) {
        float hh = hC[hm][r];
        float gg = fmaf(-hh, hh, 1.0f);
        float mm = fmaf(-2.0f * ((const float*)&cv)[r], hh, m[r]);
        qv[r] = (f16)(gg * mm);
      }
      *(f16x4*)&pb[col * S2 + 16 * hm + 4 * g4] = qv;
    }
  }

  // ===== G^T = W1x Q^T (K=128)
  f32x4 gT[2];
  gT[0] = {0.f,0.f,0.f,0.f}; gT[1] = {0.f,0.f,0.f,0.f};
  #pragma unroll
  for (int ks = 0; ks < 4; ++ks) {
    f16x8 q8 = *(const f16x8*)&pb[col * S2 + 32 * ks + 8 * g4];
    #pragma unroll
    for (int om = 0; om < 2; ++om) {
      f16x8 a = *(const f16x8*)&W1X[(16 * om + col) * S2 + 32 * ks + 8 * g4];
      gT[om] = mfma16(a, q8, gT[om]);
    }
  }

  // ===== resid = dsdt - hb*(s + G) ; L1 mean over j ; reduce 4 lane-groups
  float acc = 0.f;
  #pragma unroll
  for (int om = 0; om < 2; ++om)
    #pragma unroll
    for (int r = 0; r < 4; ++r)
      acc += fabsf(dT[om][r] - hb * (sT[om][r] + gT[om][r]));
  acc += __shfl_xor(acc, 16);
  acc += __shfl_xor(acc, 32);
  if (ln < BPW && (b0 + ln) < Btot) out[b0 + ln] = acc * (1.0f / 32.0f);
}

} // namespace

extern "C" void kernel_launch(void* const* d_in, const int* in_sizes, int n_in,
                              void* d_out, int out_size, void* d_ws, size_t ws_size,
                              hipStream_t stream) {
  const float* x    = (const float*)d_in[0];
  const float* t    = (const float*)d_in[1];
  const float* beta = (const float*)d_in[2];
  const float* W1   = (const float*)d_in[3];
  const float* b1   = (const float*)d_in[4];
  const float* W2   = (const float*)d_in[5];
  const float* b2   = (const float*)d_in[6];
  float* out = (float*)d_out;

  const int Btot = in_sizes[1];  // t is [B,1]
  const int grid = (Btot + BPB - 1) / BPB;
  hipLaunchKernelGGL(fpe_mfma, dim3(grid), dim3(THREADS), 0, stream,
                     x, t, beta, W1, b1, W2, b2, out, Btot);
}